// Round 3
// baseline (928.501 us; speedup 1.0000x reference)
//
#include <hip/hip_runtime.h>
#include <hip/hip_bf16.h>
#include <math.h>

#define HD 128
#define NN 50000
#define NE 500000
#define LN_EPS 1e-5f

typedef __attribute__((ext_vector_type(8))) short short8;
typedef __attribute__((ext_vector_type(4))) float f32x4;

__device__ __forceinline__ unsigned short f2bf(float f) {
    unsigned int u = __float_as_uint(f);
    u = (u + 0x7FFFu + ((u >> 16) & 1u)) >> 16;   // RNE truncate to bf16
    return (unsigned short)u;
}
__device__ __forceinline__ float bf2f(unsigned short b) {
    return __uint_as_float(((unsigned int)b) << 16);
}
__device__ __forceinline__ float gelu_f(float x) {
    return 0.5f * x * (1.0f + erff(x * 0.70710678118654752440f));
}
__device__ __forceinline__ float sigm_f(float x) {
    return 1.0f / (1.0f + __expf(-x));
}

// ---------------------------------------------------------------------------
// pack_kernel: pre-pack all MFMA B-fragments (bf16) in per-thread consumption
// order so compute kernels load them with coalesced dwordx4 instead of
// thousands of scattered scalar 4B loads.
//   P1: node_pre  [g=nn*4+kk][t=0..383] short8     (6144 frags)
//   P2: node_post [g=nn*8+kk][t=0..255] short8     (4096 frags)
//   P3: edge e2_W [g=nn*4+kk][t=0..255] short8     (4096 frags)
//   P4: e1c float2[lane=0..63][k=0..15]            (1024 elems)
// ---------------------------------------------------------------------------
__global__ __launch_bounds__(256) void pack_kernel(
    const float* __restrict__ src_W, const float* __restrict__ e1_W,
    const float* __restrict__ e2_W,
    const float* __restrict__ self_W, const float* __restrict__ agg_W,
    unsigned short* __restrict__ p1, unsigned short* __restrict__ p2,
    unsigned short* __restrict__ p3, float2* __restrict__ p4)
{
    const int fid = blockIdx.x * 256 + threadIdx.x;
    if (fid < 6144) {                       // P1
        const int g = fid / 384, t = fid % 384;
        const int nn = g >> 2, kk = g & 3;
        const int w = t / 64, lane = t & 63, lo = lane & 15, hi = lane >> 4;
        const int c = w * 64 + nn * 16 + lo;
        short8 v;
        #pragma unroll
        for (int j = 0; j < 8; ++j) {
            const int k = kk * 32 + hi * 8 + j;
            float wv;
            if (c < 128)      wv = src_W[k * 128 + c];
            else if (c < 256) wv = e1_W[k * 128 + (c - 128)];
            else              wv = e1_W[(128 + k) * 128 + (c - 256)];
            v[j] = (short)f2bf(wv);
        }
        *(short8*)(p1 + (g * 384 + t) * 8) = v;
    } else if (fid < 10240) {               // P2
        const int f = fid - 6144;
        const int g = f / 256, t = f % 256;
        const int nn = g >> 3, kk = g & 7;
        const int w = t / 64, lane = t & 63, lo = lane & 15, hi = lane >> 4;
        const int c = w * 32 + nn * 16 + lo;
        short8 v;
        #pragma unroll
        for (int j = 0; j < 8; ++j) {
            const int k = kk * 32 + hi * 8 + j;
            const float wv = (k < 128) ? self_W[k * 128 + c] : agg_W[(k - 128) * 128 + c];
            v[j] = (short)f2bf(wv);
        }
        *(short8*)(p2 + (g * 256 + t) * 8) = v;
    } else if (fid < 14336) {               // P3
        const int f = fid - 10240;
        const int g = f / 256, t = f % 256;
        const int nn = g >> 2, kk = g & 3;
        const int w = t / 64, lane = t & 63, lo = lane & 15, hi = lane >> 4;
        const int nbase = (nn < 2) ? (w * 32 + nn * 16) : (128 + w * 32 + (nn - 2) * 16);
        const int n = nbase + lo;
        short8 v;
        #pragma unroll
        for (int j = 0; j < 8; ++j) {
            const int k = kk * 32 + hi * 8 + j;
            v[j] = (short)f2bf(e2_W[k * 256 + n]);
        }
        *(short8*)(p3 + (g * 256 + t) * 8) = v;
    } else if (fid < 15360) {               // P4
        const int f = fid - 14336;
        const int lane = f / 16, k = f % 16;
        p4[lane * 16 + k] = make_float2(e1_W[(256 + k) * 128 + 2 * lane],
                                        e1_W[(256 + k) * 128 + 2 * lane + 1]);
    }
}

// ---------------------------------------------------------------------------
// K1: node_pre — X = h (N x128) @ [src_W | e1_Wa | e1_Wb] + bias -> bf16 tables
// per-tile grid (782 blocks), packed coalesced weight-fragment loads.
// ---------------------------------------------------------------------------
__global__ __launch_bounds__(384) void node_pre_kernel(
    const float* __restrict__ h,
    const float* __restrict__ src_b, const float* __restrict__ e1_b,
    const unsigned short* __restrict__ p1,
    unsigned short* __restrict__ hswb,
    unsigned short* __restrict__ a1b,
    unsigned short* __restrict__ b1b)
{
    const int tid = threadIdx.x;
    const int lane = tid & 63;
    const int w = tid >> 6;           // 0..5
    const int lo = lane & 15, hi = lane >> 4;
    const int m0 = blockIdx.x * 64;

    short8 bf[4][4];
    #pragma unroll
    for (int nn = 0; nn < 4; ++nn)
        #pragma unroll
        for (int kk = 0; kk < 4; ++kk)
            bf[kk][nn] = *(const short8*)(p1 + ((nn * 4 + kk) * 384 + tid) * 8);

    f32x4 acc[4][4];
    #pragma unroll
    for (int mm = 0; mm < 4; ++mm)
        #pragma unroll
        for (int nn = 0; nn < 4; ++nn)
            acc[mm][nn] = (f32x4){0.f, 0.f, 0.f, 0.f};

    #pragma unroll
    for (int mm = 0; mm < 4; ++mm) {
        int row = m0 + mm * 16 + lo;
        if (row >= NN) row = NN - 1;
        short8 af[4];
        #pragma unroll
        for (int kk = 0; kk < 4; ++kk) {
            const float* pp = h + row * 128 + kk * 32 + hi * 8;
            const float4 q0 = *(const float4*)pp;
            const float4 q1 = *(const float4*)(pp + 4);
            short8 v;
            v[0] = (short)f2bf(q0.x); v[1] = (short)f2bf(q0.y);
            v[2] = (short)f2bf(q0.z); v[3] = (short)f2bf(q0.w);
            v[4] = (short)f2bf(q1.x); v[5] = (short)f2bf(q1.y);
            v[6] = (short)f2bf(q1.z); v[7] = (short)f2bf(q1.w);
            af[kk] = v;
        }
        #pragma unroll
        for (int nn = 0; nn < 4; ++nn)
            #pragma unroll
            for (int kk = 0; kk < 4; ++kk)
                acc[mm][nn] = __builtin_amdgcn_mfma_f32_16x16x32_bf16(
                    af[kk], bf[kk][nn], acc[mm][nn], 0, 0, 0);
    }

    #pragma unroll
    for (int mm = 0; mm < 4; ++mm) {
        #pragma unroll
        for (int nn = 0; nn < 4; ++nn) {
            const int c = w * 64 + nn * 16 + lo;
            #pragma unroll
            for (int r = 0; r < 4; ++r) {
                const int row = m0 + mm * 16 + hi * 4 + r;
                if (row < NN) {
                    const float v = acc[mm][nn][r];
                    if (c < 128)      hswb[row * 128 + c]       = f2bf(v + src_b[c]);
                    else if (c < 256) a1b [row * 128 + (c-128)] = f2bf(v + e1_b[c-128]);
                    else              b1b [row * 128 + (c-256)] = f2bf(v);
                }
            }
        }
    }
}

// ---------------------------------------------------------------------------
// Sort machinery: histogram -> 1-block scan -> scatter (counting sort by dst)
// ---------------------------------------------------------------------------
__global__ __launch_bounds__(256) void hist_kernel(
    const int* __restrict__ edge_index, int* __restrict__ deg)
{
    const int e = blockIdx.x * 256 + threadIdx.x;
    if (e < NE) atomicAdd(&deg[edge_index[2 * e + 1]], 1);
}

__global__ __launch_bounds__(1024) void scan_kernel(
    const int* __restrict__ deg, int* __restrict__ cursor)
{
    __shared__ int sums[1024];
    const int t = threadIdx.x;
    const int chunk = (NN + 1023) / 1024;   // 49
    const int i0 = t * chunk;
    int s = 0;
    for (int i = 0; i < chunk; ++i) {
        const int idx = i0 + i;
        if (idx < NN) s += deg[idx];
    }
    sums[t] = s;
    __syncthreads();
    for (int off = 1; off < 1024; off <<= 1) {
        const int v = (t >= off) ? sums[t - off] : 0;
        __syncthreads();
        sums[t] += v;
        __syncthreads();
    }
    int run = (t > 0) ? sums[t - 1] : 0;
    for (int i = 0; i < chunk; ++i) {
        const int idx = i0 + i;
        if (idx < NN) {
            cursor[idx] = run;
            run += deg[idx];
        }
    }
}

__global__ __launch_bounds__(256) void scatter_kernel(
    const int* __restrict__ edge_index, int* __restrict__ cursor,
    int* __restrict__ sorted_eid)
{
    const int e = blockIdx.x * 256 + threadIdx.x;
    if (e < NE) {
        const int d = edge_index[2 * e + 1];
        const int pos = atomicAdd(&cursor[d], 1);
        sorted_eid[pos] = e;
    }
}

// ---------------------------------------------------------------------------
// K3: edge kernel, dst-sorted 64-edge tiles, software-pipelined:
//   stage(t+1) metadata/edge_attr overlaps MFMA(t); gathers prefetched 8-deep.
//   agg via 32-slot LDS tile (overflow -> direct global atomic), coalesced flush.
// ---------------------------------------------------------------------------
__global__ __launch_bounds__(256, 3) void edge_kernel(
    const float* __restrict__ edge_attr, const int* __restrict__ edge_index,
    const int* __restrict__ sorted_eid,
    const unsigned short* __restrict__ p3, const float2* __restrict__ p4,
    const float* __restrict__ e2_b,
    const unsigned short* __restrict__ hswb,
    const unsigned short* __restrict__ a1b, const unsigned short* __restrict__ b1b,
    float* __restrict__ agg, int nblocks)
{
    __shared__ unsigned int hid32[64 * 64];     // 16 KB, 16B-chunk XOR swizzle
    __shared__ float agg_tile[32 * 128];        // 16 KB
    __shared__ float4 ea4[2][64][4];            // 8 KB, double-buffered
    __shared__ int s_lds[2][64];
    __shared__ int d_lds[2][64];
    __shared__ int lid_lds[2][64];
    __shared__ int gdst_lds[2][64];
    __shared__ int ndist_lds[2];

    const int tid = threadIdx.x;
    const int lane = tid & 63;
    const int w = __builtin_amdgcn_readfirstlane(tid >> 6);  // 0..3
    const int lo = lane & 15, hi = lane >> 4;

    // e1c columns (f32 pairs) from packed table
    float2 e1c[16];
    #pragma unroll
    for (int k = 0; k < 16; ++k) e1c[k] = p4[lane * 16 + k];

    // e2_W fragments from packed table (coalesced)
    short8 bf[4][4];
    #pragma unroll
    for (int nn = 0; nn < 4; ++nn)
        #pragma unroll
        for (int kk = 0; kk < 4; ++kk)
            bf[kk][nn] = *(const short8*)(p3 + ((nn * 4 + kk) * 256 + tid) * 8);
    float bg[2], bs[2];
    #pragma unroll
    for (int nn = 0; nn < 2; ++nn) {
        bg[nn] = e2_b[w * 32 + nn * 16 + lo];
        bs[nn] = e2_b[128 + w * 32 + nn * 16 + lo];
    }

    auto stage = [&](int teb, int buf) {
        const int base = teb * 64;
        if (tid >= 64 && tid < 128) {           // resolve s/d (wave1)
            const int t = tid - 64;
            const int ti = base + t;
            int s = 0, d = -1;
            if (ti < NE) {
                const int eid = sorted_eid[ti];
                s = edge_index[2 * eid];
                d = edge_index[2 * eid + 1];
            }
            s_lds[buf][t] = s;
            d_lds[buf][t] = d;
        }
        {                                        // stage edge_attr (all threads)
            const int er = tid >> 2, q = tid & 3;
            const int ti = base + er;
            if (ti < NE) {
                const int eid = sorted_eid[ti];
                ea4[buf][er][q] = *(const float4*)(edge_attr + eid * 16 + q * 4);
            }
        }
    };

    for (int i = tid; i < 32 * 128; i += 256) agg_tile[i] = 0.f;
    int eb = blockIdx.x;
    if (eb < nblocks) stage(eb, 0);
    __syncthreads();

    int p = 0;
    for (; eb < nblocks; eb += gridDim.x) {
        const int ebase = eb * 64;

        // ---- wave0: local-dst-run scan (reads pre-staged d_lds[p]) ----
        if (w == 0) {
            const int er = lane;
            const int d = d_lds[p][er];
            const bool valid = (ebase + er < NE);
            const bool flag = valid && (er == 0 || d_lds[p][er - 1] != d);
            const unsigned long long mask = __ballot(flag ? 1 : 0);
            const unsigned long long below =
                (er == 63) ? mask : (mask & ((1ull << (er + 1)) - 1ull));
            const int lid = (int)__popcll(below) - 1;
            lid_lds[p][er] = lid;
            if (flag) gdst_lds[p][lid] = d;
            if (er == 0) ndist_lds[p] = (int)__popcll(mask);
        }

        // ---- phase A: hid rows, gathers prefetched 8-deep ----
        #pragma unroll
        for (int half = 0; half < 2; ++half) {
            unsigned int av[8], bv[8];
            #pragma unroll
            for (int u = 0; u < 8; ++u) {
                const int er = w * 16 + half * 8 + u;
                const int s = s_lds[p][er];
                int d = d_lds[p][er];
                if (d < 0) d = 0;
                av[u] = *(const unsigned int*)(a1b + s * 128 + 2 * lane);
                bv[u] = *(const unsigned int*)(b1b + d * 128 + 2 * lane);
            }
            #pragma unroll
            for (int u = 0; u < 8; ++u) {
                const int er = w * 16 + half * 8 + u;
                float t0 = bf2f((unsigned short)(av[u] & 0xFFFFu))
                         + bf2f((unsigned short)(bv[u] & 0xFFFFu));
                float t1 = bf2f((unsigned short)(av[u] >> 16))
                         + bf2f((unsigned short)(bv[u] >> 16));
                #pragma unroll
                for (int q = 0; q < 4; ++q) {
                    const float4 qa = ea4[p][er][q];
                    t0 += qa.x * e1c[4*q+0].x + qa.y * e1c[4*q+1].x
                        + qa.z * e1c[4*q+2].x + qa.w * e1c[4*q+3].x;
                    t1 += qa.x * e1c[4*q+0].y + qa.y * e1c[4*q+1].y
                        + qa.z * e1c[4*q+2].y + qa.w * e1c[4*q+3].y;
                }
                t0 = gelu_f(t0);
                t1 = gelu_f(t1);
                const unsigned int hv = (unsigned int)f2bf(t0) | ((unsigned int)f2bf(t1) << 16);
                const int chunk = (lane >> 2) ^ (er & 7);
                hid32[er * 64 + chunk * 4 + (lane & 3)] = hv;
            }
        }
        __syncthreads();   // BAR1: hid32 + lid ready; prev flush complete

        // ---- stage next tile (loads overlap MFMA below) ----
        if (eb + gridDim.x < nblocks) stage(eb + gridDim.x, p ^ 1);

        // ---- phase B + epilogue, split in two col-passes (VGPR control) ----
        #pragma unroll
        for (int np = 0; np < 2; ++np) {
            f32x4 acc[4][2];   // [mm][0=gate,1=shift]
            #pragma unroll
            for (int mm = 0; mm < 4; ++mm) {
                acc[mm][0] = (f32x4){0.f, 0.f, 0.f, 0.f};
                acc[mm][1] = (f32x4){0.f, 0.f, 0.f, 0.f};
            }
            #pragma unroll
            for (int mm = 0; mm < 4; ++mm) {
                const int row = mm * 16 + lo;
                short8 af[4];
                #pragma unroll
                for (int kk = 0; kk < 4; ++kk) {
                    const int sb = ((kk * 4 + hi) ^ (row & 7)) << 4;
                    af[kk] = *(const short8*)((const char*)hid32 + row * 256 + sb);
                }
                #pragma unroll
                for (int kk = 0; kk < 4; ++kk) {
                    acc[mm][0] = __builtin_amdgcn_mfma_f32_16x16x32_bf16(
                        af[kk], bf[kk][np], acc[mm][0], 0, 0, 0);
                    acc[mm][1] = __builtin_amdgcn_mfma_f32_16x16x32_bf16(
                        af[kk], bf[kk][np + 2], acc[mm][1], 0, 0, 0);
                }
            }
            const int c = w * 32 + np * 16 + lo;
            #pragma unroll
            for (int mm = 0; mm < 4; ++mm) {
                float pend = 0.f;
                int plid = -1;
                #pragma unroll
                for (int r = 0; r < 4; ++r) {
                    const int er = mm * 16 + hi * 4 + r;
                    if (ebase + er < NE) {
                        const int s = s_lds[p][er];
                        const float g  = acc[mm][0][r] + bg[np];
                        const float sh = acc[mm][1][r] + bs[np];
                        const float msg = sigm_f(g) * bf2f(hswb[s * 128 + c]) + sh;
                        const int lid = lid_lds[p][er];
                        if (lid != plid) {
                            if (plid >= 0) {
                                if (plid < 32) atomicAdd(&agg_tile[plid * 128 + c], pend);
                                else unsafeAtomicAdd(&agg[gdst_lds[p][plid] * 128 + c], pend);
                            }
                            plid = lid; pend = 0.f;
                        }
                        pend += msg;
                    }
                }
                if (plid >= 0) {
                    if (plid < 32) atomicAdd(&agg_tile[plid * 128 + c], pend);
                    else unsafeAtomicAdd(&agg[gdst_lds[p][plid] * 128 + c], pend);
                }
            }
        }
        __syncthreads();   // BAR2: agg_tile done; staged LDS for next tile done

        // ---- flush: coalesced global atomics; re-zero ----
        const int nd = min(ndist_lds[p], 32);
        for (int i = tid; i < nd * 128; i += 256) {
            const float v = agg_tile[i];
            agg_tile[i] = 0.f;
            unsafeAtomicAdd(&agg[gdst_lds[p][i >> 7] * 128 + (i & 127)], v);
        }
        p ^= 1;
    }
}

// ---------------------------------------------------------------------------
// K4: node_post — update = [h | agg/deg] @ [self_W; agg_W] + biases;
//     x = h + gelu(update); LayerNorm -> out.  Per-tile grid, packed weights.
// ---------------------------------------------------------------------------
__global__ __launch_bounds__(256) void node_post_kernel(
    const float* __restrict__ h,
    const float* __restrict__ self_b, const float* __restrict__ agg_b,
    const float* __restrict__ ln_g, const float* __restrict__ ln_b,
    const float* __restrict__ agg, const int* __restrict__ deg,
    const unsigned short* __restrict__ p2,
    float* __restrict__ out)
{
    __shared__ float x_lds[64 * 129];
    const int tid = threadIdx.x;
    const int lane = tid & 63;
    const int w = tid >> 6;          // 0..3
    const int lo = lane & 15, hi = lane >> 4;
    const int m0 = blockIdx.x * 64;

    short8 bf[8][2];
    #pragma unroll
    for (int nn = 0; nn < 2; ++nn)
        #pragma unroll
        for (int kk = 0; kk < 8; ++kk)
            bf[kk][nn] = *(const short8*)(p2 + ((nn * 8 + kk) * 256 + tid) * 8);

    f32x4 acc[4][2];
    #pragma unroll
    for (int mm = 0; mm < 4; ++mm)
        #pragma unroll
        for (int nn = 0; nn < 2; ++nn)
            acc[mm][nn] = (f32x4){0.f, 0.f, 0.f, 0.f};

    #pragma unroll
    for (int mm = 0; mm < 4; ++mm) {
        int row = m0 + mm * 16 + lo;
        if (row >= NN) row = NN - 1;
        const float rdeg = 1.0f / fmaxf((float)deg[row], 1.0f);
        short8 af[8];
        #pragma unroll
        for (int kk = 0; kk < 4; ++kk) {
            const float* pp = h + row * 128 + kk * 32 + hi * 8;
            const float4 q0 = *(const float4*)pp;
            const float4 q1 = *(const float4*)(pp + 4);
            short8 v;
            v[0] = (short)f2bf(q0.x); v[1] = (short)f2bf(q0.y);
            v[2] = (short)f2bf(q0.z); v[3] = (short)f2bf(q0.w);
            v[4] = (short)f2bf(q1.x); v[5] = (short)f2bf(q1.y);
            v[6] = (short)f2bf(q1.z); v[7] = (short)f2bf(q1.w);
            af[kk] = v;
        }
        #pragma unroll
        for (int kk = 4; kk < 8; ++kk) {
            const float* pp = agg + row * 128 + (kk - 4) * 32 + hi * 8;
            const float4 q0 = *(const float4*)pp;
            const float4 q1 = *(const float4*)(pp + 4);
            short8 v;
            v[0] = (short)f2bf(q0.x * rdeg); v[1] = (short)f2bf(q0.y * rdeg);
            v[2] = (short)f2bf(q0.z * rdeg); v[3] = (short)f2bf(q0.w * rdeg);
            v[4] = (short)f2bf(q1.x * rdeg); v[5] = (short)f2bf(q1.y * rdeg);
            v[6] = (short)f2bf(q1.z * rdeg); v[7] = (short)f2bf(q1.w * rdeg);
            af[kk] = v;
        }
        #pragma unroll
        for (int nn = 0; nn < 2; ++nn)
            #pragma unroll
            for (int kk = 0; kk < 8; ++kk)
                acc[mm][nn] = __builtin_amdgcn_mfma_f32_16x16x32_bf16(
                    af[kk], bf[kk][nn], acc[mm][nn], 0, 0, 0);
    }

    #pragma unroll
    for (int mm = 0; mm < 4; ++mm) {
        #pragma unroll
        for (int nn = 0; nn < 2; ++nn) {
            const int c = w * 32 + nn * 16 + lo;
            const float bsum = self_b[c] + agg_b[c];
            #pragma unroll
            for (int r = 0; r < 4; ++r) {
                const int rl = mm * 16 + hi * 4 + r;
                int row = m0 + rl;
                if (row >= NN) row = NN - 1;
                const float upd = acc[mm][nn][r] + bsum;
                x_lds[rl * 129 + c] = h[row * 128 + c] + gelu_f(upd);
            }
        }
    }
    __syncthreads();

    const int rrow = tid >> 2;
    const int part = tid & 3;
    float sum = 0.f, ss = 0.f;
    #pragma unroll
    for (int i = 0; i < 32; ++i) {
        const float v = x_lds[rrow * 129 + part * 32 + i];
        sum += v; ss += v * v;
    }
    sum += __shfl_xor(sum, 1); ss += __shfl_xor(ss, 1);
    sum += __shfl_xor(sum, 2); ss += __shfl_xor(ss, 2);
    const float mu = sum * (1.0f / 128.0f);
    const float var = ss * (1.0f / 128.0f) - mu * mu;
    const float rstd = rsqrtf(var + LN_EPS);
    const int grow = m0 + rrow;
    if (grow < NN) {
        #pragma unroll
        for (int i = 0; i < 32; ++i) {
            const int c = part * 32 + i;
            const float v = x_lds[rrow * 129 + c];
            out[grow * 128 + c] = (v - mu) * rstd * ln_g[c] + ln_b[c];
        }
    }
}

// ---------------------------------------------------------------------------
extern "C" void kernel_launch(void* const* d_in, const int* in_sizes, int n_in,
                              void* d_out, int out_size, void* d_ws, size_t ws_size,
                              hipStream_t stream) {
    const float* h         = (const float*)d_in[0];
    const float* edge_attr = (const float*)d_in[1];
    const int*   edge_index= (const int*)  d_in[2];
    const float* src_W     = (const float*)d_in[3];
    const float* src_b     = (const float*)d_in[4];
    const float* e1_W      = (const float*)d_in[5];
    const float* e1_b      = (const float*)d_in[6];
    const float* e2_W      = (const float*)d_in[7];
    const float* e2_b      = (const float*)d_in[8];
    const float* self_W    = (const float*)d_in[9];
    const float* self_b    = (const float*)d_in[10];
    const float* agg_W     = (const float*)d_in[11];
    const float* agg_b     = (const float*)d_in[12];
    const float* ln_g      = (const float*)d_in[13];
    const float* ln_b      = (const float*)d_in[14];
    float* out = (float*)d_out;

    char* ws = (char*)d_ws;
    unsigned short* hswb = (unsigned short*)(ws);               // N*128 bf16
    unsigned short* a1b  = (unsigned short*)(ws + 12800000);    // N*128 bf16
    unsigned short* b1b  = (unsigned short*)(ws + 25600000);    // N*128 bf16
    float* agg        = (float*)(ws + 38400000);                // N*128 f32
    int*   deg        = (int*)  (ws + 64000000);                // N int
    int*   cursor     = (int*)  (ws + 64200000);                // N int
    int*   sorted_eid = (int*)  (ws + 64400000);                // E int
    unsigned short* p1 = (unsigned short*)(ws + 66400000);      // 98.3 KB
    unsigned short* p2 = (unsigned short*)(ws + 66500000);      // 64 KB
    unsigned short* p3 = (unsigned short*)(ws + 66600000);      // 64 KB
    float2*         p4 = (float2*)        (ws + 66700000);      // 2 KB

    hipMemsetAsync(agg, 0, 25600000 + 200000, stream);          // agg + deg

    pack_kernel<<<60, 256, 0, stream>>>(src_W, e1_W, e2_W, self_W, agg_W,
                                        p1, p2, p3, p4);

    node_pre_kernel<<<(NN + 63) / 64, 384, 0, stream>>>(
        h, src_b, e1_b, p1, hswb, a1b, b1b);

    hist_kernel<<<(NE + 255) / 256, 256, 0, stream>>>(edge_index, deg);
    scan_kernel<<<1, 1024, 0, stream>>>(deg, cursor);
    scatter_kernel<<<(NE + 255) / 256, 256, 0, stream>>>(edge_index, cursor, sorted_eid);

    const int nblocks = (NE + 63) / 64;   // 7813
    edge_kernel<<<768, 256, 0, stream>>>(
        edge_attr, edge_index, sorted_eid, p3, p4, e2_b,
        hswb, a1b, b1b, agg, nblocks);

    node_post_kernel<<<(NN + 63) / 64, 256, 0, stream>>>(
        h, self_b, agg_b, ln_g, ln_b, agg, deg, p2, out);
}

// Round 4
// 614.395 us; speedup vs baseline: 1.5112x; 1.5112x over previous
//
#include <hip/hip_runtime.h>
#include <hip/hip_bf16.h>
#include <math.h>

#define NN 50000
#define NE 500000
#define LN_EPS 1e-5f

typedef __attribute__((ext_vector_type(8))) short short8;
typedef __attribute__((ext_vector_type(4))) float f32x4;

__device__ __forceinline__ unsigned short f2bf(float f) {
    unsigned int u = __float_as_uint(f);
    u = (u + 0x7FFFu + ((u >> 16) & 1u)) >> 16;   // RNE truncate to bf16
    return (unsigned short)u;
}
__device__ __forceinline__ float bf2f(unsigned short b) {
    return __uint_as_float(((unsigned int)b) << 16);
}
__device__ __forceinline__ float sigm_f(float x) {
    return 1.0f / (1.0f + __expf(-x));
}
// tanh-approx GELU via 0.5*(1+tanh(y)) == sigmoid(2y); |err| <= ~3e-3
__device__ __forceinline__ float gelu_fast(float x) {
    return x * sigm_f(1.5957691f * fmaf(0.044715f * x * x, x, x));
}

// ---------------------------------------------------------------------------
// pack_kernel: pre-pack all MFMA B-fragments (bf16) in per-thread consumption
// order (coalesced dwordx4 loads in the compute kernels).
// ---------------------------------------------------------------------------
__global__ __launch_bounds__(256) void pack_kernel(
    const float* __restrict__ src_W, const float* __restrict__ e1_W,
    const float* __restrict__ e2_W,
    const float* __restrict__ self_W, const float* __restrict__ agg_W,
    unsigned short* __restrict__ p1, unsigned short* __restrict__ p2,
    unsigned short* __restrict__ p3, float2* __restrict__ p4)
{
    const int fid = blockIdx.x * 256 + threadIdx.x;
    if (fid < 6144) {                       // P1: node_pre
        const int g = fid / 384, t = fid % 384;
        const int nn = g >> 2, kk = g & 3;
        const int w = t / 64, lane = t & 63, lo = lane & 15, hi = lane >> 4;
        const int c = w * 64 + nn * 16 + lo;
        short8 v;
        #pragma unroll
        for (int j = 0; j < 8; ++j) {
            const int k = kk * 32 + hi * 8 + j;
            float wv;
            if (c < 128)      wv = src_W[k * 128 + c];
            else if (c < 256) wv = e1_W[k * 128 + (c - 128)];
            else              wv = e1_W[(128 + k) * 128 + (c - 256)];
            v[j] = (short)f2bf(wv);
        }
        *(short8*)(p1 + (g * 384 + t) * 8) = v;
    } else if (fid < 10240) {               // P2: node_post
        const int f = fid - 6144;
        const int g = f / 256, t = f % 256;
        const int nn = g >> 3, kk = g & 7;
        const int w = t / 64, lane = t & 63, lo = lane & 15, hi = lane >> 4;
        const int c = w * 32 + nn * 16 + lo;
        short8 v;
        #pragma unroll
        for (int j = 0; j < 8; ++j) {
            const int k = kk * 32 + hi * 8 + j;
            const float wv = (k < 128) ? self_W[k * 128 + c] : agg_W[(k - 128) * 128 + c];
            v[j] = (short)f2bf(wv);
        }
        *(short8*)(p2 + (g * 256 + t) * 8) = v;
    } else if (fid < 14336) {               // P3: edge e2_W
        const int f = fid - 10240;
        const int g = f / 256, t = f % 256;
        const int nn = g >> 2, kk = g & 3;
        const int w = t / 64, lane = t & 63, lo = lane & 15, hi = lane >> 4;
        const int nbase = (nn < 2) ? (w * 32 + nn * 16) : (128 + w * 32 + (nn - 2) * 16);
        const int n = nbase + lo;
        short8 v;
        #pragma unroll
        for (int j = 0; j < 8; ++j) {
            const int k = kk * 32 + hi * 8 + j;
            v[j] = (short)f2bf(e2_W[k * 256 + n]);
        }
        *(short8*)(p3 + (g * 256 + t) * 8) = v;
    } else if (fid < 15360) {               // P4: e1_W edge-attr cols, f32 pairs
        const int f = fid - 14336;
        const int lane = f / 16, k = f % 16;
        p4[lane * 16 + k] = make_float2(e1_W[(256 + k) * 128 + 2 * lane],
                                        e1_W[(256 + k) * 128 + 2 * lane + 1]);
    }
}

// ---------------------------------------------------------------------------
// K1: node_pre — X = h (N x128) @ [src_W | e1_Wa | e1_Wb] + bias -> bf16 tables
// ---------------------------------------------------------------------------
__global__ __launch_bounds__(384) void node_pre_kernel(
    const float* __restrict__ h,
    const float* __restrict__ src_b, const float* __restrict__ e1_b,
    const unsigned short* __restrict__ p1,
    unsigned short* __restrict__ hswb,
    unsigned short* __restrict__ a1b,
    unsigned short* __restrict__ b1b)
{
    const int tid = threadIdx.x;
    const int lane = tid & 63;
    const int w = tid >> 6;           // 0..5
    const int lo = lane & 15, hi = lane >> 4;
    const int m0 = blockIdx.x * 64;

    short8 bf[4][4];
    #pragma unroll
    for (int nn = 0; nn < 4; ++nn)
        #pragma unroll
        for (int kk = 0; kk < 4; ++kk)
            bf[kk][nn] = *(const short8*)(p1 + ((nn * 4 + kk) * 384 + tid) * 8);

    f32x4 acc[4][4];
    #pragma unroll
    for (int mm = 0; mm < 4; ++mm)
        #pragma unroll
        for (int nn = 0; nn < 4; ++nn)
            acc[mm][nn] = (f32x4){0.f, 0.f, 0.f, 0.f};

    #pragma unroll
    for (int mm = 0; mm < 4; ++mm) {
        int row = m0 + mm * 16 + lo;
        if (row >= NN) row = NN - 1;
        short8 af[4];
        #pragma unroll
        for (int kk = 0; kk < 4; ++kk) {
            const float* pp = h + row * 128 + kk * 32 + hi * 8;
            const float4 q0 = *(const float4*)pp;
            const float4 q1 = *(const float4*)(pp + 4);
            short8 v;
            v[0] = (short)f2bf(q0.x); v[1] = (short)f2bf(q0.y);
            v[2] = (short)f2bf(q0.z); v[3] = (short)f2bf(q0.w);
            v[4] = (short)f2bf(q1.x); v[5] = (short)f2bf(q1.y);
            v[6] = (short)f2bf(q1.z); v[7] = (short)f2bf(q1.w);
            af[kk] = v;
        }
        #pragma unroll
        for (int nn = 0; nn < 4; ++nn)
            #pragma unroll
            for (int kk = 0; kk < 4; ++kk)
                acc[mm][nn] = __builtin_amdgcn_mfma_f32_16x16x32_bf16(
                    af[kk], bf[kk][nn], acc[mm][nn], 0, 0, 0);
    }

    #pragma unroll
    for (int mm = 0; mm < 4; ++mm) {
        #pragma unroll
        for (int nn = 0; nn < 4; ++nn) {
            const int c = w * 64 + nn * 16 + lo;
            #pragma unroll
            for (int r = 0; r < 4; ++r) {
                const int row = m0 + mm * 16 + hi * 4 + r;
                if (row < NN) {
                    const float v = acc[mm][nn][r];
                    if (c < 128)      hswb[row * 128 + c]       = f2bf(v + src_b[c]);
                    else if (c < 256) a1b [row * 128 + (c-128)] = f2bf(v + e1_b[c-128]);
                    else              b1b [row * 128 + (c-256)] = f2bf(v);
                }
            }
        }
    }
}

// ---------------------------------------------------------------------------
// Sort machinery: histogram -> 1-block scan -> scatter+pregather
// ---------------------------------------------------------------------------
__global__ __launch_bounds__(256) void hist_kernel(
    const int* __restrict__ edge_index, int* __restrict__ deg)
{
    const int e = blockIdx.x * 256 + threadIdx.x;
    if (e < NE) atomicAdd(&deg[edge_index[2 * e + 1]], 1);
}

__global__ __launch_bounds__(1024) void scan_kernel(
    const int* __restrict__ deg, int* __restrict__ cursor)
{
    __shared__ int sums[1024];
    const int t = threadIdx.x;
    const int chunk = (NN + 1023) / 1024;   // 49
    const int i0 = t * chunk;
    int s = 0;
    for (int i = 0; i < chunk; ++i) {
        const int idx = i0 + i;
        if (idx < NN) s += deg[idx];
    }
    sums[t] = s;
    __syncthreads();
    for (int off = 1; off < 1024; off <<= 1) {
        const int v = (t >= off) ? sums[t - off] : 0;
        __syncthreads();
        sums[t] += v;
        __syncthreads();
    }
    int run = (t > 0) ? sums[t - 1] : 0;
    for (int i = 0; i < chunk; ++i) {
        const int idx = i0 + i;
        if (idx < NN) {
            cursor[idx] = run;
            run += deg[idx];
        }
    }
}

// scatter + pre-gather: emit dst-sorted s/d streams and bf16 edge_attr rows
__global__ __launch_bounds__(256) void scatter_kernel(
    const int* __restrict__ edge_index, const float* __restrict__ edge_attr,
    int* __restrict__ cursor,
    int* __restrict__ s_sorted, int* __restrict__ d_sorted,
    unsigned short* __restrict__ ea_sorted)
{
    const int e = blockIdx.x * 256 + threadIdx.x;
    if (e < NE) {
        const int s = edge_index[2 * e];
        const int d = edge_index[2 * e + 1];
        const int pos = atomicAdd(&cursor[d], 1);
        s_sorted[pos] = s;
        d_sorted[pos] = d;
        const float4 q0 = *(const float4*)(edge_attr + e * 16);
        const float4 q1 = *(const float4*)(edge_attr + e * 16 + 4);
        const float4 q2 = *(const float4*)(edge_attr + e * 16 + 8);
        const float4 q3 = *(const float4*)(edge_attr + e * 16 + 12);
        short8 vl, vh;
        vl[0] = (short)f2bf(q0.x); vl[1] = (short)f2bf(q0.y);
        vl[2] = (short)f2bf(q0.z); vl[3] = (short)f2bf(q0.w);
        vl[4] = (short)f2bf(q1.x); vl[5] = (short)f2bf(q1.y);
        vl[6] = (short)f2bf(q1.z); vl[7] = (short)f2bf(q1.w);
        vh[0] = (short)f2bf(q2.x); vh[1] = (short)f2bf(q2.y);
        vh[2] = (short)f2bf(q2.z); vh[3] = (short)f2bf(q2.w);
        vh[4] = (short)f2bf(q3.x); vh[5] = (short)f2bf(q3.y);
        vh[6] = (short)f2bf(q3.z); vh[7] = (short)f2bf(q3.w);
        *(short8*)(ea_sorted + (size_t)pos * 16)     = vl;
        *(short8*)(ea_sorted + (size_t)pos * 16 + 8) = vh;
    }
}

// ---------------------------------------------------------------------------
// K3: edge kernel — dst-sorted 64-edge tiles, contiguous chunk per block.
//   All streams coalesced (s/d/ea pre-sorted); only a1/b1/hsw row-gathers.
//   hsw rows staged in LDS during phase A; epilogue: run-compacted atomics.
// ---------------------------------------------------------------------------
__global__ __launch_bounds__(256, 2) void edge_kernel(
    const unsigned short* __restrict__ ea_sorted,
    const int* __restrict__ s_sorted, const int* __restrict__ d_sorted,
    const unsigned short* __restrict__ p3, const float2* __restrict__ p4,
    const float* __restrict__ e2_b,
    const unsigned short* __restrict__ hswb,
    const unsigned short* __restrict__ a1b, const unsigned short* __restrict__ b1b,
    float* __restrict__ agg, int nblocks)
{
    __shared__ unsigned int hid32[64 * 64];   // hid bf16 pairs, chunk-XOR swizzle
    __shared__ unsigned int hswt[64 * 64];    // hsw bf16 pairs, word-XOR swizzle
    __shared__ int s_lds[2][64];
    __shared__ int d_lds[2][64];

    const int tid = threadIdx.x;
    const int lane = tid & 63;
    const int w = __builtin_amdgcn_readfirstlane(tid >> 6);  // 0..3
    const int lo = lane & 15, hi = lane >> 4;

    float2 e1c[16];
    #pragma unroll
    for (int k = 0; k < 16; ++k) e1c[k] = p4[lane * 16 + k];

    short8 bf[4][4];
    #pragma unroll
    for (int nn = 0; nn < 4; ++nn)
        #pragma unroll
        for (int kk = 0; kk < 4; ++kk)
            bf[kk][nn] = *(const short8*)(p3 + ((nn * 4 + kk) * 256 + tid) * 8);
    float bg[2], bs[2];
    #pragma unroll
    for (int nn = 0; nn < 2; ++nn) {
        bg[nn] = e2_b[w * 32 + nn * 16 + lo];
        bs[nn] = e2_b[128 + w * 32 + nn * 16 + lo];
    }

    // contiguous chunk of tiles per block (dst-locality + disjoint atomics)
    const int chunk = (nblocks + (int)gridDim.x - 1) / (int)gridDim.x;
    const int t0 = blockIdx.x * chunk;
    const int t1 = min(t0 + chunk, nblocks);
    if (t0 >= t1) return;

    if (tid < 64) {
        const int ti = t0 * 64 + tid;
        s_lds[0][tid] = (ti < NE) ? s_sorted[ti] : 0;
        d_lds[0][tid] = (ti < NE) ? d_sorted[ti] : -1;
    }
    __syncthreads();

    int p = 0;
    for (int t = t0; t < t1; ++t) {
        const long base = (long)t * 64;

        // ---- phase A: 16 edges/wave, gathers prefetched 8-deep ----
        #pragma unroll
        for (int half = 0; half < 2; ++half) {
            unsigned int av[8], bv[8], hv[8];
            #pragma unroll
            for (int u = 0; u < 8; ++u) {
                const int er = w * 16 + half * 8 + u;
                const int s = s_lds[p][er];
                int d = d_lds[p][er]; if (d < 0) d = 0;
                av[u] = *(const unsigned int*)(a1b  + (size_t)s * 128 + 2 * lane);
                bv[u] = *(const unsigned int*)(b1b  + (size_t)d * 128 + 2 * lane);
                hv[u] = *(const unsigned int*)(hswb + (size_t)s * 128 + 2 * lane);
            }
            #pragma unroll
            for (int u = 0; u < 8; ++u) {
                const int er = w * 16 + half * 8 + u;
                hswt[er * 64 + (lane ^ (((er >> 2) & 3) << 3))] = hv[u];
                float tA = bf2f((unsigned short)(av[u] & 0xFFFFu))
                         + bf2f((unsigned short)(bv[u] & 0xFFFFu));
                float tB = bf2f((unsigned short)(av[u] >> 16))
                         + bf2f((unsigned short)(bv[u] >> 16));
                const short8 eaL = *(const short8*)(ea_sorted + (base + er) * 16);
                const short8 eaH = *(const short8*)(ea_sorted + (base + er) * 16 + 8);
                #pragma unroll
                for (int k = 0; k < 8; ++k) {
                    const float e = bf2f((unsigned short)eaL[k]);
                    tA = fmaf(e, e1c[k].x, tA);
                    tB = fmaf(e, e1c[k].y, tB);
                }
                #pragma unroll
                for (int k = 0; k < 8; ++k) {
                    const float e = bf2f((unsigned short)eaH[k]);
                    tA = fmaf(e, e1c[8 + k].x, tA);
                    tB = fmaf(e, e1c[8 + k].y, tB);
                }
                tA = gelu_fast(tA);
                tB = gelu_fast(tB);
                const unsigned int hp = (unsigned int)f2bf(tA) | ((unsigned int)f2bf(tB) << 16);
                const int ch = (lane >> 2) ^ (er & 7);
                hid32[er * 64 + ch * 4 + (lane & 3)] = hp;
            }
        }

        // issue next tile's s/d loads (land after BAR2's ds_write)
        int sN = 0, dN = -1;
        const bool more = (t + 1 < t1);
        if (more && tid < 64) {
            const int ti = (t + 1) * 64 + tid;
            if (ti < NE) { sN = s_sorted[ti]; dN = d_sorted[ti]; }
        }
        __syncthreads();   // BAR1: hid32 + hswt complete

        // ---- phase B: 64 MFMA/wave ----
        f32x4 acc[4][4];
        #pragma unroll
        for (int mm = 0; mm < 4; ++mm)
            #pragma unroll
            for (int nn = 0; nn < 4; ++nn)
                acc[mm][nn] = (f32x4){0.f, 0.f, 0.f, 0.f};

        #pragma unroll
        for (int mm = 0; mm < 4; ++mm) {
            const int row = mm * 16 + lo;
            short8 af[4];
            #pragma unroll
            for (int kk = 0; kk < 4; ++kk) {
                const int sb = ((kk * 4 + hi) ^ (row & 7)) << 4;
                af[kk] = *(const short8*)((const char*)hid32 + row * 256 + sb);
            }
            #pragma unroll
            for (int nn = 0; nn < 4; ++nn)
                #pragma unroll
                for (int kk = 0; kk < 4; ++kk)
                    acc[mm][nn] = __builtin_amdgcn_mfma_f32_16x16x32_bf16(
                        af[kk], bf[kk][nn], acc[mm][nn], 0, 0, 0);
        }

        // ---- epilogue: run-compacted direct atomics ----
        #pragma unroll
        for (int mm = 0; mm < 4; ++mm) {
            #pragma unroll
            for (int nn = 0; nn < 2; ++nn) {
                const int c = w * 32 + nn * 16 + lo;
                int pd = -1;
                float pend = 0.f;
                #pragma unroll
                for (int r = 0; r < 4; ++r) {
                    const int er = mm * 16 + hi * 4 + r;
                    const int d = d_lds[p][er];
                    if (d >= 0) {
                        const float g  = acc[mm][nn][r]     + bg[nn];
                        const float sh = acc[mm][nn + 2][r] + bs[nn];
                        const unsigned int hw =
                            hswt[er * 64 + ((c >> 1) ^ (((er >> 2) & 3) << 3))];
                        const float hval =
                            bf2f((unsigned short)((c & 1) ? (hw >> 16) : (hw & 0xFFFFu)));
                        const float msg = sigm_f(g) * hval + sh;
                        if (d != pd) {
                            if (pd >= 0) unsafeAtomicAdd(&agg[(size_t)pd * 128 + c], pend);
                            pd = d; pend = 0.f;
                        }
                        pend += msg;
                    }
                }
                if (pd >= 0) unsafeAtomicAdd(&agg[(size_t)pd * 128 + c], pend);
            }
        }

        if (more && tid < 64) {
            s_lds[p ^ 1][tid] = sN;
            d_lds[p ^ 1][tid] = dN;
        }
        __syncthreads();   // BAR2: epilogue done; next s/d staged
        p ^= 1;
    }
}

// ---------------------------------------------------------------------------
// K4: node_post — update = [h | agg/deg] @ [self_W; agg_W] + biases;
//     x = h + gelu(update); LayerNorm -> out.
// ---------------------------------------------------------------------------
__global__ __launch_bounds__(256) void node_post_kernel(
    const float* __restrict__ h,
    const float* __restrict__ self_b, const float* __restrict__ agg_b,
    const float* __restrict__ ln_g, const float* __restrict__ ln_b,
    const float* __restrict__ agg, const int* __restrict__ deg,
    const unsigned short* __restrict__ p2,
    float* __restrict__ out)
{
    __shared__ float x_lds[64 * 129];
    const int tid = threadIdx.x;
    const int lane = tid & 63;
    const int w = tid >> 6;          // 0..3
    const int lo = lane & 15, hi = lane >> 4;
    const int m0 = blockIdx.x * 64;

    short8 bf[8][2];
    #pragma unroll
    for (int nn = 0; nn < 2; ++nn)
        #pragma unroll
        for (int kk = 0; kk < 8; ++kk)
            bf[kk][nn] = *(const short8*)(p2 + ((nn * 8 + kk) * 256 + tid) * 8);

    f32x4 acc[4][2];
    #pragma unroll
    for (int mm = 0; mm < 4; ++mm)
        #pragma unroll
        for (int nn = 0; nn < 2; ++nn)
            acc[mm][nn] = (f32x4){0.f, 0.f, 0.f, 0.f};

    #pragma unroll
    for (int mm = 0; mm < 4; ++mm) {
        int row = m0 + mm * 16 + lo;
        if (row >= NN) row = NN - 1;
        const float rdeg = 1.0f / fmaxf((float)deg[row], 1.0f);
        short8 af[8];
        #pragma unroll
        for (int kk = 0; kk < 4; ++kk) {
            const float* pp = h + row * 128 + kk * 32 + hi * 8;
            const float4 q0 = *(const float4*)pp;
            const float4 q1 = *(const float4*)(pp + 4);
            short8 v;
            v[0] = (short)f2bf(q0.x); v[1] = (short)f2bf(q0.y);
            v[2] = (short)f2bf(q0.z); v[3] = (short)f2bf(q0.w);
            v[4] = (short)f2bf(q1.x); v[5] = (short)f2bf(q1.y);
            v[6] = (short)f2bf(q1.z); v[7] = (short)f2bf(q1.w);
            af[kk] = v;
        }
        #pragma unroll
        for (int kk = 4; kk < 8; ++kk) {
            const float* pp = agg + row * 128 + (kk - 4) * 32 + hi * 8;
            const float4 q0 = *(const float4*)pp;
            const float4 q1 = *(const float4*)(pp + 4);
            short8 v;
            v[0] = (short)f2bf(q0.x * rdeg); v[1] = (short)f2bf(q0.y * rdeg);
            v[2] = (short)f2bf(q0.z * rdeg); v[3] = (short)f2bf(q0.w * rdeg);
            v[4] = (short)f2bf(q1.x * rdeg); v[5] = (short)f2bf(q1.y * rdeg);
            v[6] = (short)f2bf(q1.z * rdeg); v[7] = (short)f2bf(q1.w * rdeg);
            af[kk] = v;
        }
        #pragma unroll
        for (int nn = 0; nn < 2; ++nn)
            #pragma unroll
            for (int kk = 0; kk < 8; ++kk)
                acc[mm][nn] = __builtin_amdgcn_mfma_f32_16x16x32_bf16(
                    af[kk], bf[kk][nn], acc[mm][nn], 0, 0, 0);
    }

    #pragma unroll
    for (int mm = 0; mm < 4; ++mm) {
        #pragma unroll
        for (int nn = 0; nn < 2; ++nn) {
            const int c = w * 32 + nn * 16 + lo;
            const float bsum = self_b[c] + agg_b[c];
            #pragma unroll
            for (int r = 0; r < 4; ++r) {
                const int rl = mm * 16 + hi * 4 + r;
                int row = m0 + rl;
                if (row >= NN) row = NN - 1;
                const float upd = acc[mm][nn][r] + bsum;
                x_lds[rl * 129 + c] = h[row * 128 + c] + gelu_fast(upd);
            }
        }
    }
    __syncthreads();

    const int rrow = tid >> 2;
    const int part = tid & 3;
    float sum = 0.f, ss = 0.f;
    #pragma unroll
    for (int i = 0; i < 32; ++i) {
        const float v = x_lds[rrow * 129 + part * 32 + i];
        sum += v; ss += v * v;
    }
    sum += __shfl_xor(sum, 1); ss += __shfl_xor(ss, 1);
    sum += __shfl_xor(sum, 2); ss += __shfl_xor(ss, 2);
    const float mu = sum * (1.0f / 128.0f);
    const float var = ss * (1.0f / 128.0f) - mu * mu;
    const float rstd = rsqrtf(var + LN_EPS);
    const int grow = m0 + rrow;
    if (grow < NN) {
        #pragma unroll
        for (int i = 0; i < 32; ++i) {
            const int c = part * 32 + i;
            const float v = x_lds[rrow * 129 + c];
            out[grow * 128 + c] = (v - mu) * rstd * ln_g[c] + ln_b[c];
        }
    }
}

// ---------------------------------------------------------------------------
extern "C" void kernel_launch(void* const* d_in, const int* in_sizes, int n_in,
                              void* d_out, int out_size, void* d_ws, size_t ws_size,
                              hipStream_t stream) {
    const float* h         = (const float*)d_in[0];
    const float* edge_attr = (const float*)d_in[1];
    const int*   edge_index= (const int*)  d_in[2];
    const float* src_W     = (const float*)d_in[3];
    const float* src_b     = (const float*)d_in[4];
    const float* e1_W      = (const float*)d_in[5];
    const float* e1_b      = (const float*)d_in[6];
    const float* e2_W      = (const float*)d_in[7];
    const float* e2_b      = (const float*)d_in[8];
    const float* self_W    = (const float*)d_in[9];
    const float* self_b    = (const float*)d_in[10];
    const float* agg_W     = (const float*)d_in[11];
    const float* agg_b     = (const float*)d_in[12];
    const float* ln_g      = (const float*)d_in[13];
    const float* ln_b      = (const float*)d_in[14];
    float* out = (float*)d_out;

    char* ws = (char*)d_ws;
    unsigned short* hswb = (unsigned short*)(ws);               // 12.8 MB
    unsigned short* a1b  = (unsigned short*)(ws + 12800000);    // 12.8 MB
    unsigned short* b1b  = (unsigned short*)(ws + 25600000);    // 12.8 MB
    float* agg         = (float*)(ws + 38400000);               // 25.6 MB
    int*   deg         = (int*)  (ws + 64000000);               // 0.2 MB
    int*   cursor      = (int*)  (ws + 64200000);               // 0.2 MB
    int*   s_sorted    = (int*)  (ws + 64400000);               // 2 MB
    int*   d_sorted    = (int*)  (ws + 66400000);               // 2 MB
    unsigned short* p1 = (unsigned short*)(ws + 68400000);      // 98.3 KB
    unsigned short* p2 = (unsigned short*)(ws + 68500000);      // 64 KB
    unsigned short* p3 = (unsigned short*)(ws + 68600000);      // 64 KB
    float2*         p4 = (float2*)        (ws + 68700000);      // 8 KB
    unsigned short* ea_sorted = (unsigned short*)(ws + 68710000); // 16 MB + tail

    // zero agg + deg (contiguous)
    hipMemsetAsync(agg, 0, 25600000 + 200000, stream);

    pack_kernel<<<60, 256, 0, stream>>>(src_W, e1_W, e2_W, self_W, agg_W,
                                        p1, p2, p3, p4);

    hist_kernel<<<(NE + 255) / 256, 256, 0, stream>>>(edge_index, deg);
    scan_kernel<<<1, 1024, 0, stream>>>(deg, cursor);
    scatter_kernel<<<(NE + 255) / 256, 256, 0, stream>>>(
        edge_index, edge_attr, cursor, s_sorted, d_sorted, ea_sorted);

    node_pre_kernel<<<(NN + 63) / 64, 384, 0, stream>>>(
        h, src_b, e1_b, p1, hswb, a1b, b1b);

    const int nblocks = (NE + 63) / 64;   // 7813
    edge_kernel<<<512, 256, 0, stream>>>(
        ea_sorted, s_sorted, d_sorted, p3, p4, e2_b,
        hswb, a1b, b1b, agg, nblocks);

    node_post_kernel<<<(NN + 63) / 64, 256, 0, stream>>>(
        h, self_b, agg_b, ln_g, ln_b, agg, deg, p2, out);
}